// Round 20
// baseline (114.961 us; speedup 1.0000x reference)
//
#include <hip/hip_runtime.h>
#include <math.h>

#define E_DIM 64
#define N_E   1024
#define BETA  0.25
#define NROWS 65536

using bf16x8 = __attribute__((ext_vector_type(8))) short;
using f32x4  = __attribute__((ext_vector_type(4))) float;
#define MFMA(a, b, c) __builtin_amdgcn_mfma_f32_16x16x32_bf16((a), (b), (c), 0, 0, 0)

// ---------------------------------------------------------------------------
// Numerics contract (idx must match the fp32 numpy reference exactly):
//   exact score_j = (nz + h_j) - m_ij, m = sequential fp32 FMA chain (round-3
//   proven on all 65536 rows). MFMA path: 6-deep MFMA C-in chain (fixed
//   order, deterministic; reorder noise ~1e-8 << Delta slack). Rows with
//   merged (2nd - best) <= Delta_row = 6e-8*Sum|z| + 2.2e-5 flagged -> exact
//   k_cleanup re-scan (wave/row, tie -> lower j == np.argmin).
// Round-20: split-K x4 IN-BLOCK. 8-wave block covers 64 rows; wave w =
//   (row-group w&1, codebook QUARTER w>>1), 16 col-tiles/wave. Grid 1024 =
//   4 blocks/CU = 32 waves/CU (theoretical 100% occupancy; round 19 was
//   grid-capped at 50%). Per-wave register state identical to round 16/19
//   (no allocator risk). Merge over 4 ascending quarters (strict <, lowest
//   quarter wins = first-index, proven pattern). Epilogue 8 threads/row.
//
// ws: [0,4096) hist | [4096] sse f64 | [4104] flagN u32 | [4112,8208) h f32
//     [8208) ebh bf16[65536] | [139280) ebl | [270352) flagL u32[65536]
//     end 532496
// ---------------------------------------------------------------------------

__device__ __forceinline__ unsigned short f2bf_rn(float f) {
    unsigned u = __builtin_bit_cast(unsigned, f);
    unsigned r = u + 0x7fffu + ((u >> 16) & 1u);
    return (unsigned short)(r >> 16);
}
__device__ __forceinline__ float bf2f(unsigned short b) {
    unsigned u = ((unsigned)b) << 16;
    return __builtin_bit_cast(float, u);
}

__device__ __forceinline__ float pw64_sq(const float* v) {
    float r[8];
#pragma unroll
    for (int l = 0; l < 8; ++l) r[l] = v[l] * v[l];
#pragma unroll
    for (int t = 1; t < 8; ++t)
#pragma unroll
        for (int l = 0; l < 8; ++l) r[l] += v[8 * t + l] * v[8 * t + l];
    return ((r[0] + r[1]) + (r[2] + r[3])) + ((r[4] + r[5]) + (r[6] + r[7]));
}

// Fused prep: pack B-fragments (all blocks), h (blocks 0-3), zero (4-5).
__global__ __launch_bounds__(256) void k_prep(const float* __restrict__ cb,
                                              unsigned short* __restrict__ ebh,
                                              unsigned short* __restrict__ ebl,
                                              float* __restrict__ h,
                                              unsigned* __restrict__ hist,
                                              double* __restrict__ sse,
                                              unsigned* __restrict__ flagN) {
    int t = blockIdx.x * 256 + threadIdx.x;
    {   // pack: linear t = ct*1024 + ks*512 + lane*8 + e
        int e = t & 7, lane = (t >> 3) & 63, ks = (t >> 9) & 1, ct = t >> 10;
        int j = ct * 16 + (lane & 15);
        int k = ks * 32 + ((lane >> 4) << 3) + e;
        float v = cb[j * 64 + k];
        unsigned short hi = f2bf_rn(v);
        ebh[t] = hi;
        ebl[t] = f2bf_rn(v - bf2f(hi));
    }
    if (blockIdx.x < 4) {                       // h_j, exact pairwise-8
        int j = t;
        float e[E_DIM];
        const float4* ep = reinterpret_cast<const float4*>(cb + (size_t)j * E_DIM);
#pragma unroll
        for (int k4 = 0; k4 < E_DIM / 4; ++k4) {
            float4 v = ep[k4];
            e[4 * k4 + 0] = v.x; e[4 * k4 + 1] = v.y;
            e[4 * k4 + 2] = v.z; e[4 * k4 + 3] = v.w;
        }
        h[j] = pw64_sq(e);
    } else if (blockIdx.x == 4) {
#pragma unroll
        for (int u = 0; u < 4; ++u) hist[threadIdx.x * 4 + u] = 0u;
    } else if (blockIdx.x == 5 && threadIdx.x == 0) {
        *sse = 0.0;
        *flagN = 0u;
    }
}

// Block = 8 waves (512 thr) = 64 rows. Wave w: rows [(w&1)*32, +32),
// codebook quarter (w>>1). Round-16 scan machinery, quarter-sized span.
__global__ __launch_bounds__(512, 4) void k_mfma(
    const float* __restrict__ z, const float* __restrict__ cb,
    const float* __restrict__ h,
    const unsigned short* __restrict__ ebh, const unsigned short* __restrict__ ebl,
    float* __restrict__ out_zq, float* __restrict__ out_idx,
    unsigned* __restrict__ hist, double* __restrict__ sse,
    unsigned* __restrict__ flagN, unsigned* __restrict__ flagL) {
    const int lane = threadIdx.x & 63;
    const int w = __builtin_amdgcn_readfirstlane(threadIdx.x >> 6);
    const int m = lane & 15, g = lane >> 4;
    const int q4 = w >> 1;                      // codebook quarter 0..3
    const int rw = w & 1;                       // row wave within block

    __shared__ int bok;
    __shared__ float sh_h[N_E];
    __shared__ float rsv[64];
    __shared__ float sb0[4][64], sb1[4][64];
    __shared__ int   sbi[4][64];
    __shared__ float wp[8];
    if (threadIdx.x == 0) bok = 1;
    for (int i = threadIdx.x; i < N_E; i += 512) sh_h[i] = h[i];
    __syncthreads();

    // ---- MFMA layout self-test (asymmetric integer patterns, exact) ----
    {
        bf16x8 a, b;
#pragma unroll
        for (int e = 0; e < 8; ++e) {
            int k = g * 8 + e;
            a[e] = (short)f2bf_rn((float)(((m * 3 + k * 7) & 15) - 7));
            b[e] = (short)f2bf_rn((float)(((k * 5 + m * 3) & 15) - 8));
        }
        f32x4 acc = {0.f, 0.f, 0.f, 0.f};
        acc = MFMA(a, b, acc);
        bool ok = true;
#pragma unroll
        for (int r = 0; r < 4; ++r) {
            int rr = g * 4 + r;
            float E = 0.f;
            for (int k = 0; k < 32; ++k)
                E += (float)((((rr * 3 + k * 7) & 15) - 7) * (((k * 5 + m * 3) & 15) - 8));
            ok = ok && (acc[r] == E);
        }
        if (!ok) atomicAnd(&bok, 0);
    }
    __syncthreads();
    if (!bok) {   // layout wrong: flag all 64 rows -> exact cleanup handles them
        if (threadIdx.x < 64) {
            unsigned p = atomicAdd(flagN, 1u);
            flagL[p] = (unsigned)(blockIdx.x * 64 + threadIdx.x);
        }
        return;
    }

    // ---- A-load: 2 tiles of z rows, hi/lo split of 2z, per-row Sum|z| ----
    const int rowb32 = blockIdx.x * 64 + rw * 32;
    bf16x8 a0h0, a0l0, a0h1, a0l1, a1h0, a1l0, a1h1, a1l1;
#define ALOAD(P, AH0, AL0, AH1, AL1) {                                         \
        const int rowA = rowb32 + (P) * 16 + m;                                \
        const float4* zr = reinterpret_cast<const float4*>(z + (size_t)rowA * 64); \
        float4 p0 = zr[g * 2], p1 = zr[g * 2 + 1];                             \
        float4 p2 = zr[8 + g * 2], p3 = zr[9 + g * 2];                         \
        float t0[8] = {p0.x, p0.y, p0.z, p0.w, p1.x, p1.y, p1.z, p1.w};        \
        float t1[8] = {p2.x, p2.y, p2.z, p2.w, p3.x, p3.y, p3.z, p3.w};        \
        float s = 0.f;                                                         \
        _Pragma("unroll")                                                      \
        for (int e = 0; e < 8; ++e) {                                          \
            s += fabsf(t0[e]) + fabsf(t1[e]);                                  \
            float x0 = 2.0f * t0[e]; unsigned short h0 = f2bf_rn(x0);          \
            AH0[e] = (short)h0; AL0[e] = (short)f2bf_rn(x0 - bf2f(h0));        \
            float x1 = 2.0f * t1[e]; unsigned short h1 = f2bf_rn(x1);          \
            AH1[e] = (short)h1; AL1[e] = (short)f2bf_rn(x1 - bf2f(h1));        \
        }                                                                      \
        s += __shfl_xor(s, 16);                                                \
        s += __shfl_xor(s, 32);                                                \
        if (g == 0 && q4 == 0) rsv[rw * 32 + (P) * 16 + m] = s;                \
    }
    ALOAD(0, a0h0, a0l0, a0h1, a0l1)
    ALOAD(1, a1h0, a1l0, a1h1, a1l1)
#undef ALOAD

    // ---- scan: 16 col-tiles (this quarter), 2-buffer register prefetch ----
    float bb00 = INFINITY, bb01 = INFINITY, bb02 = INFINITY, bb03 = INFINITY;
    float bb10 = INFINITY, bb11 = INFINITY, bb12 = INFINITY, bb13 = INFINITY;
    float ss00 = INFINITY, ss01 = INFINITY, ss02 = INFINITY, ss03 = INFINITY;
    float ss10 = INFINITY, ss11 = INFINITY, ss12 = INFINITY, ss13 = INFINITY;
    int   ii00 = 0, ii01 = 0, ii02 = 0, ii03 = 0;
    int   ii10 = 0, ii11 = 0, ii12 = 0, ii13 = 0;
#define UPD(S, B0, B1, I0) { float _s = (S);                                   \
        if (_s < B0) { B1 = B0; B0 = _s; I0 = j; } else B1 = fminf(B1, _s); }

    const bf16x8* pBh = reinterpret_cast<const bf16x8*>(ebh);
    const bf16x8* pBl = reinterpret_cast<const bf16x8*>(ebl);
    const int ct0 = q4 * 16;

    bf16x8 Ah0 = pBh[ct0 * 128 + lane],        Ah1 = pBh[ct0 * 128 + lane + 64];
    bf16x8 Al0 = pBl[ct0 * 128 + lane],        Al1 = pBl[ct0 * 128 + lane + 64];
    bf16x8 Bh0 = pBh[(ct0 + 1) * 128 + lane],  Bh1 = pBh[(ct0 + 1) * 128 + lane + 64];
    bf16x8 Bl0 = pBl[(ct0 + 1) * 128 + lane],  Bl1 = pBl[(ct0 + 1) * 128 + lane + 64];

    // 6-deep C-in accumulation chain (fixed order, deterministic)
#define COLTILE(CT, VH0, VH1, VL0, VL1) {                                      \
        const int j = (CT) * 16 + m;                                           \
        const float hj = sh_h[j];                                              \
        const f32x4 z4 = {0.f, 0.f, 0.f, 0.f};                                 \
        f32x4 s0 = MFMA(a0h0, VH0, z4);                                        \
        f32x4 s1 = MFMA(a1h0, VH0, z4);                                        \
        s0 = MFMA(a0h1, VH1, s0);                                              \
        s1 = MFMA(a1h1, VH1, s1);                                              \
        s0 = MFMA(a0h0, VL0, s0);                                              \
        s1 = MFMA(a1h0, VL0, s1);                                              \
        s0 = MFMA(a0h1, VL1, s0);                                              \
        s1 = MFMA(a1h1, VL1, s1);                                              \
        s0 = MFMA(a0l0, VH0, s0);                                              \
        s1 = MFMA(a1l0, VH0, s1);                                              \
        s0 = MFMA(a0l1, VH1, s0);                                              \
        s1 = MFMA(a1l1, VH1, s1);                                              \
        UPD(hj - s0[0], bb00, ss00, ii00)                                      \
        UPD(hj - s0[1], bb01, ss01, ii01)                                      \
        UPD(hj - s0[2], bb02, ss02, ii02)                                      \
        UPD(hj - s0[3], bb03, ss03, ii03)                                      \
        UPD(hj - s1[0], bb10, ss10, ii10)                                      \
        UPD(hj - s1[1], bb11, ss11, ii11)                                      \
        UPD(hj - s1[2], bb12, ss12, ii12)                                      \
        UPD(hj - s1[3], bb13, ss13, ii13)                                      \
    }

#pragma unroll 1
    for (int ct = ct0; ct < ct0 + 16; ct += 2) {
        COLTILE(ct, Ah0, Ah1, Al0, Al1);
        if (ct + 2 < ct0 + 16) {
            const int fb = (ct + 2) * 128 + lane;
            Ah0 = pBh[fb]; Ah1 = pBh[fb + 64];
            Al0 = pBl[fb]; Al1 = pBl[fb + 64];
        }
        COLTILE(ct + 1, Bh0, Bh1, Bl0, Bl1);
        if (ct + 3 < ct0 + 16) {
            const int fb = (ct + 3) * 128 + lane;
            Bh0 = pBh[fb]; Bh1 = pBh[fb + 64];
            Bl0 = pBl[fb]; Bl1 = pBl[fb + 64];
        }
    }
#undef COLTILE
#undef UPD

    // ---- reduce best/2nd across the 16 col-lanes of each group ----
#pragma unroll
    for (int mask = 1; mask < 16; mask <<= 1) {
#define MRG(B0, I0, B1) { float ob0 = __shfl_xor(B0, mask); int oi = __shfl_xor(I0, mask); \
        float ob1 = __shfl_xor(B1, mask); \
        if (ob0 < B0) { B1 = fminf(fminf(B0, B1), ob1); B0 = ob0; I0 = oi; } \
        else { B1 = fminf(B1, fminf(ob0, ob1)); } }
        MRG(bb00, ii00, ss00) MRG(bb01, ii01, ss01)
        MRG(bb02, ii02, ss02) MRG(bb03, ii03, ss03)
        MRG(bb10, ii10, ss10) MRG(bb11, ii11, ss11)
        MRG(bb12, ii12, ss12) MRG(bb13, ii13, ss13)
#undef MRG
    }

    // ---- publish per-row partials to LDS (m==0 lane of each group) ----
    if (m == 0) {
        const int r0 = rw * 32 + g * 4;
        sb0[q4][r0 + 0] = bb00; sb1[q4][r0 + 0] = ss00; sbi[q4][r0 + 0] = ii00;
        sb0[q4][r0 + 1] = bb01; sb1[q4][r0 + 1] = ss01; sbi[q4][r0 + 1] = ii01;
        sb0[q4][r0 + 2] = bb02; sb1[q4][r0 + 2] = ss02; sbi[q4][r0 + 2] = ii02;
        sb0[q4][r0 + 3] = bb03; sb1[q4][r0 + 3] = ss03; sbi[q4][r0 + 3] = ii03;
        const int r1 = r0 + 16;
        sb0[q4][r1 + 0] = bb10; sb1[q4][r1 + 0] = ss10; sbi[q4][r1 + 0] = ii10;
        sb0[q4][r1 + 1] = bb11; sb1[q4][r1 + 1] = ss11; sbi[q4][r1 + 1] = ii11;
        sb0[q4][r1 + 2] = bb12; sb1[q4][r1 + 2] = ss12; sbi[q4][r1 + 2] = ii12;
        sb0[q4][r1 + 3] = bb13; sb1[q4][r1 + 3] = ss13; sbi[q4][r1 + 3] = ii13;
    }
    __syncthreads();

    // ---- merge 4 quarters + epilogue: 8 threads per row (512 thr / 64 rows) ----
    {
        const int rloc = threadIdx.x >> 3, q = threadIdx.x & 7;
        const int rowO = blockIdx.x * 64 + rloc;
        float b0 = sb0[0][rloc], b1 = sb1[0][rloc];
        int   vi = sbi[0][rloc];
#pragma unroll
        for (int c = 1; c < 4; ++c) {          // ascending quarter order
            float c0 = sb0[c][rloc], c1 = sb1[c][rloc];
            int   ci = sbi[c][rloc];
            if (c0 < b0) { b1 = fminf(b0, c1); b0 = c0; vi = ci; }
            else         { b1 = fminf(b1, fminf(c0, c1)); }   // tie -> lower quarter
        }
        const float Delta = 6e-8f * rsv[rloc] + 2.2e-5f;
        float local = 0.f;
        if (b1 - b0 <= Delta) {
            if (q == 0) { unsigned p = atomicAdd(flagN, 1u); flagL[p] = (unsigned)rowO; }
        } else {
            if (q == 0) { out_idx[rowO] = (float)vi; atomicAdd(&hist[vi], 1u); }
            const float4* cv = reinterpret_cast<const float4*>(cb + (size_t)vi * 64) + q * 2;
            const float4* zv = reinterpret_cast<const float4*>(z + (size_t)rowO * 64) + q * 2;
            float* orow = out_zq + (size_t)rowO * 64 + q * 8;
#pragma unroll
            for (int u = 0; u < 2; ++u) {
                float4 cc = cv[u], zo = zv[u];
                orow[4 * u + 0] = cc.x; orow[4 * u + 1] = cc.y;
                orow[4 * u + 2] = cc.z; orow[4 * u + 3] = cc.w;
                float dx = cc.x - zo.x, dy = cc.y - zo.y;
                float dz = cc.z - zo.z, dw = cc.w - zo.w;
                local = fmaf(dx, dx, local); local = fmaf(dy, dy, local);
                local = fmaf(dz, dz, local); local = fmaf(dw, dw, local);
            }
        }
#pragma unroll
        for (int off = 32; off; off >>= 1) local += __shfl_down(local, off);
        if (lane == 0) wp[w] = local;
    }
    __syncthreads();
    if (threadIdx.x == 0) {
        float t = ((wp[0] + wp[1]) + (wp[2] + wp[3]))
                + ((wp[4] + wp[5]) + (wp[6] + wp[7]));
        atomicAdd(sse, (double)t);
    }
}

// Exact re-scan for flagged rows: one wave per row, 16 codes per lane.
__global__ __launch_bounds__(64, 4) void k_cleanup(
    const float* __restrict__ z, const float* __restrict__ cb,
    const float* __restrict__ h,
    const unsigned* __restrict__ flagN, const unsigned* __restrict__ flagL,
    float* __restrict__ out_zq, float* __restrict__ out_idx,
    unsigned* __restrict__ hist, double* __restrict__ sse) {
    const unsigned n = *flagN;
    const int lane = threadIdx.x;

    for (unsigned f = blockIdx.x; f < n; f += gridDim.x) {
        const int row = (int)flagL[f];

        float tz[E_DIM];
        const float4* zp = reinterpret_cast<const float4*>(z + (size_t)row * 64);
#pragma unroll
        for (int k4 = 0; k4 < 16; ++k4) {
            float4 v = zp[k4];
            tz[4 * k4 + 0] = v.x; tz[4 * k4 + 1] = v.y;
            tz[4 * k4 + 2] = v.z; tz[4 * k4 + 3] = v.w;
        }
        const float nz = pw64_sq(tz);
#pragma unroll
        for (int k = 0; k < 64; ++k) tz[k] = 2.0f * tz[k];

        float bs = INFINITY;
        int bj = 0;
#pragma unroll 2
        for (int t = 0; t < 16; ++t) {
            const int j = lane + 64 * t;
            const float4* cv = reinterpret_cast<const float4*>(cb + (size_t)j * 64);
            float mm = 0.f;
#pragma unroll
            for (int k4 = 0; k4 < 16; ++k4) {
                float4 e = cv[k4];
                mm = fmaf(tz[4 * k4 + 0], e.x, mm);
                mm = fmaf(tz[4 * k4 + 1], e.y, mm);
                mm = fmaf(tz[4 * k4 + 2], e.z, mm);
                mm = fmaf(tz[4 * k4 + 3], e.w, mm);
            }
            float sc = (nz + h[j]) - mm;
            if (sc < bs) { bs = sc; bj = j; }
        }
#pragma unroll
        for (int off = 32; off; off >>= 1) {
            float s2 = __shfl_down(bs, off);
            int   j2 = __shfl_down(bj, off);
            if (s2 < bs || (s2 == bs && j2 < bj)) { bs = s2; bj = j2; }
        }
        bj = __shfl(bj, 0);

        float c = cb[(size_t)bj * 64 + lane];
        out_zq[(size_t)row * 64 + lane] = c;
        float d = c - 0.5f * tz[lane];
        float l2 = d * d;
#pragma unroll
        for (int off = 32; off; off >>= 1) l2 += __shfl_down(l2, off);
        if (lane == 0) {
            out_idx[row] = (float)bj;
            atomicAdd(&hist[bj], 1u);
            atomicAdd(sse, (double)l2);
        }
    }
}

// ---- round-5 fallback scan (only if ws_size is too small) ----
__global__ __launch_bounds__(256) void k_h_fb(const float* __restrict__ cb,
                                              float* __restrict__ h) {
    int j = blockIdx.x * 256 + threadIdx.x;
    if (j < N_E) {
        float e[E_DIM];
        const float4* ep = reinterpret_cast<const float4*>(cb + (size_t)j * E_DIM);
#pragma unroll
        for (int k4 = 0; k4 < E_DIM / 4; ++k4) {
            float4 v = ep[k4];
            e[4 * k4 + 0] = v.x; e[4 * k4 + 1] = v.y;
            e[4 * k4 + 2] = v.z; e[4 * k4 + 3] = v.w;
        }
        h[j] = pw64_sq(e);
    }
}

__global__ __launch_bounds__(512, 2) void k_scan_fb(
    const float* __restrict__ z, const float* __restrict__ cb,
    const float* __restrict__ h,
    float* __restrict__ out_zq, float* __restrict__ out_idx,
    unsigned* __restrict__ hist, double* __restrict__ sse) {
    const int lane = threadIdx.x & 63;
    const int w = __builtin_amdgcn_readfirstlane(threadIdx.x >> 6);
    const int row = blockIdx.x * 64 + lane;
    float tz[E_DIM];
    const float4* zp = reinterpret_cast<const float4*>(z + (size_t)row * E_DIM);
#pragma unroll
    for (int k4 = 0; k4 < E_DIM / 4; ++k4) {
        float4 v = zp[k4];
        tz[4 * k4 + 0] = v.x; tz[4 * k4 + 1] = v.y;
        tz[4 * k4 + 2] = v.z; tz[4 * k4 + 3] = v.w;
    }
    const float nz = pw64_sq(tz);
#pragma unroll
    for (int k = 0; k < E_DIM; ++k) tz[k] = 2.0f * tz[k];
    float b0 = INFINITY; int bi = 0;
    const int j0 = w * 128;
#pragma unroll 1
    for (int j = j0; j < j0 + 128; j += 4) {
        const float* c0 = cb + (size_t)j * E_DIM;
        float m0 = 0.f, m1 = 0.f, m2 = 0.f, m3 = 0.f;
#pragma unroll
        for (int k = 0; k < E_DIM; ++k) {
            float wk = tz[k];
            m0 = fmaf(wk, c0[0 * E_DIM + k], m0);
            m1 = fmaf(wk, c0[1 * E_DIM + k], m1);
            m2 = fmaf(wk, c0[2 * E_DIM + k], m2);
            m3 = fmaf(wk, c0[3 * E_DIM + k], m3);
        }
        float s0 = (nz + h[j + 0]) - m0;
        float s1 = (nz + h[j + 1]) - m1;
        float s2 = (nz + h[j + 2]) - m2;
        float s3 = (nz + h[j + 3]) - m3;
        if (s0 < b0) { b0 = s0; bi = j + 0; }
        if (s1 < b0) { b0 = s1; bi = j + 1; }
        if (s2 < b0) { b0 = s2; bi = j + 2; }
        if (s3 < b0) { b0 = s3; bi = j + 3; }
    }
    __shared__ float lb[8][64];
    __shared__ int   li[8][64];
    lb[w][lane] = b0; li[w][lane] = bi;
    __syncthreads();
    if (threadIdx.x < 64) {
        float b = lb[0][lane]; int i = li[0][lane];
#pragma unroll
        for (int c = 1; c < 8; ++c) {
            float bc = lb[c][lane]; int ic = li[c][lane];
            if (bc < b) { b = bc; i = ic; }
        }
        out_idx[row] = (float)i;
        float local = 0.f;
        const float4* cv = reinterpret_cast<const float4*>(cb + (size_t)i * E_DIM);
        float* orow = out_zq + (size_t)row * E_DIM;
#pragma unroll
        for (int k4 = 0; k4 < E_DIM / 4; ++k4) {
            float4 c = cv[k4];
            float zx = 0.5f * tz[4 * k4 + 0], zy = 0.5f * tz[4 * k4 + 1];
            float zz = 0.5f * tz[4 * k4 + 2], zw = 0.5f * tz[4 * k4 + 3];
            orow[4 * k4 + 0] = c.x; orow[4 * k4 + 1] = c.y;
            orow[4 * k4 + 2] = c.z; orow[4 * k4 + 3] = c.w;
            float dx = c.x - zx, dy = c.y - zy, dz = c.z - zz, dw = c.w - zw;
            local = fmaf(dx, dx, local); local = fmaf(dy, dy, local);
            local = fmaf(dz, dz, local); local = fmaf(dw, dw, local);
        }
        atomicAdd(&hist[i], 1u);
#pragma unroll
        for (int off = 32; off; off >>= 1) local += __shfl_down(local, off);
        if (lane == 0) atomicAdd(sse, (double)local);
    }
}

__global__ __launch_bounds__(256) void k_final(
    const unsigned* __restrict__ hist, const double* __restrict__ sse,
    float* __restrict__ out, int nrows) {
    __shared__ double sh[256];
    double acc = 0.0;
    for (int j = threadIdx.x; j < N_E; j += 256) {
        double p = (double)hist[j] / (double)nrows;
        acc += p * log(p + 1e-10);
    }
    sh[threadIdx.x] = acc;
    __syncthreads();
    for (int s = 128; s; s >>= 1) {
        if (threadIdx.x < s) sh[threadIdx.x] += sh[threadIdx.x + s];
        __syncthreads();
    }
    if (threadIdx.x == 0) {
        double ntot = (double)nrows * (double)E_DIM;
        out[0] = (float)((1.0 + BETA) * (*sse) / ntot);               // loss
        out[1 + (size_t)nrows * E_DIM] = (float)exp(-sh[0]);          // perplexity
    }
}

extern "C" void kernel_launch(void* const* d_in, const int* in_sizes, int n_in,
                              void* d_out, int out_size, void* d_ws, size_t ws_size,
                              hipStream_t stream) {
    const float* z  = (const float*)d_in[0];
    const float* cb = (const float*)d_in[1];
    const int nrows = in_sizes[0] / E_DIM;   // 65536
    float* out = (float*)d_out;

    char* ws = (char*)d_ws;
    unsigned* hist  = (unsigned*)(ws + 0);
    double*   sse   = (double*)  (ws + 4096);
    unsigned* flagN = (unsigned*)(ws + 4104);
    float*    h     = (float*)   (ws + 4112);
    unsigned short* ebh = (unsigned short*)(ws + 8208);
    unsigned short* ebl = (unsigned short*)(ws + 139280);
    unsigned* flagL = (unsigned*)(ws + 270352);   // 256 KB
    // end of ws use: 270352 + 262144 = 532496 bytes

    float* out_zq  = out + 1;
    float* out_idx = out + 1 + (size_t)nrows * E_DIM + 1;

    if (ws_size >= 532496) {
        k_prep<<<256, 256, 0, stream>>>(cb, ebh, ebl, h, hist, sse, flagN);
        k_mfma<<<nrows / 64, 512, 0, stream>>>(z, cb, h, ebh, ebl,
                                               out_zq, out_idx, hist, sse,
                                               flagN, flagL);
        k_cleanup<<<2048, 64, 0, stream>>>(z, cb, h, flagN, flagL,
                                           out_zq, out_idx, hist, sse);
    } else {
        hipMemsetAsync(d_ws, 0, 4112, stream);
        k_h_fb<<<(N_E + 255) / 256, 256, 0, stream>>>(cb, h);
        k_scan_fb<<<nrows / 64, 512, 0, stream>>>(z, cb, h, out_zq, out_idx, hist, sse);
    }
    k_final<<<1, 256, 0, stream>>>(hist, sse, out, nrows);
}

// Round 21
// 102.070 us; speedup vs baseline: 1.1263x; 1.1263x over previous
//
#include <hip/hip_runtime.h>
#include <math.h>

#define E_DIM 64
#define N_E   1024
#define BETA  0.25
#define NROWS 65536

using bf16x8 = __attribute__((ext_vector_type(8))) short;
using f32x4  = __attribute__((ext_vector_type(4))) float;
#define MFMA(a, b, c) __builtin_amdgcn_mfma_f32_16x16x32_bf16((a), (b), (c), 0, 0, 0)

// ---------------------------------------------------------------------------
// FINAL CONFIG (= round 19, best measured: 102.4us, pass, no spill).
// Numerics contract (idx must match the fp32 numpy reference exactly):
//   exact score_j = (nz + h_j) - m_ij, m = sequential fp32 FMA chain (round-3
//   proven on all 65536 rows). MFMA path: 6-deep MFMA C-in chain (fixed
//   order, deterministic; reorder noise ~1e-8 << Delta slack). Rows with
//   merged (2nd - best) <= Delta_row = 6e-8*Sum|z| + 2.2e-5 flagged -> exact
//   k_cleanup re-scan (wave/row, tie -> lower j == np.argmin).
// Structure: 8-wave blocks, 128 rows/block, in-block split-K x2 (wave w:
//   rows [(w&3)*32,+32), codebook half w>>2), 2-buffer register prefetch,
//   sh_h LDS staging, in-block merge+epilogue. Grid 512.
// Ceiling rationale (r14-r20): deeper ILP -> VGPR cliff (r17); counted-vmcnt
//   pipeline -> spill (r14); split-K x4 TLP -> overhead amortization loss
//   (r20); kernel fusion -> allocator cliffs (r12, r18). Scan floor ~25-30us
//   vs 57us achieved; residual is un-hideable L2 round-trip per col-tile at
//   the 6-VGPR-margin register budget.
//
// ws: [0,4096) hist | [4096] sse f64 | [4104] flagN u32 | [4112,8208) h f32
//     [8208) ebh bf16[65536] | [139280) ebl | [270352) flagL u32[65536]
//     end 532496
// ---------------------------------------------------------------------------

__device__ __forceinline__ unsigned short f2bf_rn(float f) {
    unsigned u = __builtin_bit_cast(unsigned, f);
    unsigned r = u + 0x7fffu + ((u >> 16) & 1u);
    return (unsigned short)(r >> 16);
}
__device__ __forceinline__ float bf2f(unsigned short b) {
    unsigned u = ((unsigned)b) << 16;
    return __builtin_bit_cast(float, u);
}

__device__ __forceinline__ float pw64_sq(const float* v) {
    float r[8];
#pragma unroll
    for (int l = 0; l < 8; ++l) r[l] = v[l] * v[l];
#pragma unroll
    for (int t = 1; t < 8; ++t)
#pragma unroll
        for (int l = 0; l < 8; ++l) r[l] += v[8 * t + l] * v[8 * t + l];
    return ((r[0] + r[1]) + (r[2] + r[3])) + ((r[4] + r[5]) + (r[6] + r[7]));
}

// Fused prep: pack B-fragments (all blocks), h (blocks 0-3), zero (4-5).
__global__ __launch_bounds__(256) void k_prep(const float* __restrict__ cb,
                                              unsigned short* __restrict__ ebh,
                                              unsigned short* __restrict__ ebl,
                                              float* __restrict__ h,
                                              unsigned* __restrict__ hist,
                                              double* __restrict__ sse,
                                              unsigned* __restrict__ flagN) {
    int t = blockIdx.x * 256 + threadIdx.x;
    {   // pack: linear t = ct*1024 + ks*512 + lane*8 + e
        int e = t & 7, lane = (t >> 3) & 63, ks = (t >> 9) & 1, ct = t >> 10;
        int j = ct * 16 + (lane & 15);
        int k = ks * 32 + ((lane >> 4) << 3) + e;
        float v = cb[j * 64 + k];
        unsigned short hi = f2bf_rn(v);
        ebh[t] = hi;
        ebl[t] = f2bf_rn(v - bf2f(hi));
    }
    if (blockIdx.x < 4) {                       // h_j, exact pairwise-8
        int j = t;
        float e[E_DIM];
        const float4* ep = reinterpret_cast<const float4*>(cb + (size_t)j * E_DIM);
#pragma unroll
        for (int k4 = 0; k4 < E_DIM / 4; ++k4) {
            float4 v = ep[k4];
            e[4 * k4 + 0] = v.x; e[4 * k4 + 1] = v.y;
            e[4 * k4 + 2] = v.z; e[4 * k4 + 3] = v.w;
        }
        h[j] = pw64_sq(e);
    } else if (blockIdx.x == 4) {
#pragma unroll
        for (int u = 0; u < 4; ++u) hist[threadIdx.x * 4 + u] = 0u;
    } else if (blockIdx.x == 5 && threadIdx.x == 0) {
        *sse = 0.0;
        *flagN = 0u;
    }
}

// Block = 8 waves (512 thr) = 128 rows. Wave w: rows [(w&3)*32, +32),
// codebook half (w>>2). Round-16 structure + sh_h LDS staging (zero-VGPR).
__global__ __launch_bounds__(512, 4) void k_mfma(
    const float* __restrict__ z, const float* __restrict__ cb,
    const float* __restrict__ h,
    const unsigned short* __restrict__ ebh, const unsigned short* __restrict__ ebl,
    float* __restrict__ out_zq, float* __restrict__ out_idx,
    unsigned* __restrict__ hist, double* __restrict__ sse,
    unsigned* __restrict__ flagN, unsigned* __restrict__ flagL) {
    const int lane = threadIdx.x & 63;
    const int w = __builtin_amdgcn_readfirstlane(threadIdx.x >> 6);
    const int m = lane & 15, g = lane >> 4;
    const int half = w >> 2;                    // 0: codes [0,512), 1: [512,1024)
    const int rw   = w & 3;                     // row wave within block

    __shared__ int bok;
    __shared__ float sh_h[N_E];
    __shared__ float rsv[128];
    __shared__ float sb0[2][128], sb1[2][128];
    __shared__ int   sbi[2][128];
    __shared__ float wp[8];
    if (threadIdx.x == 0) bok = 1;
    for (int i = threadIdx.x; i < N_E; i += 512) sh_h[i] = h[i];
    __syncthreads();

    // ---- MFMA layout self-test (asymmetric integer patterns, exact) ----
    {
        bf16x8 a, b;
#pragma unroll
        for (int e = 0; e < 8; ++e) {
            int k = g * 8 + e;
            a[e] = (short)f2bf_rn((float)(((m * 3 + k * 7) & 15) - 7));
            b[e] = (short)f2bf_rn((float)(((k * 5 + m * 3) & 15) - 8));
        }
        f32x4 acc = {0.f, 0.f, 0.f, 0.f};
        acc = MFMA(a, b, acc);
        bool ok = true;
#pragma unroll
        for (int r = 0; r < 4; ++r) {
            int rr = g * 4 + r;
            float E = 0.f;
            for (int k = 0; k < 32; ++k)
                E += (float)((((rr * 3 + k * 7) & 15) - 7) * (((k * 5 + m * 3) & 15) - 8));
            ok = ok && (acc[r] == E);
        }
        if (!ok) atomicAnd(&bok, 0);
    }
    __syncthreads();
    if (!bok) {   // layout wrong: flag all 128 rows -> exact cleanup handles them
        if (threadIdx.x < 128) {
            unsigned p = atomicAdd(flagN, 1u);
            flagL[p] = (unsigned)(blockIdx.x * 128 + threadIdx.x);
        }
        return;
    }

    // ---- A-load: 2 tiles of z rows, hi/lo split of 2z, per-row Sum|z| ----
    const int rowb32 = blockIdx.x * 128 + rw * 32;
    bf16x8 a0h0, a0l0, a0h1, a0l1, a1h0, a1l0, a1h1, a1l1;
#define ALOAD(P, AH0, AL0, AH1, AL1) {                                         \
        const int rowA = rowb32 + (P) * 16 + m;                                \
        const float4* zr = reinterpret_cast<const float4*>(z + (size_t)rowA * 64); \
        float4 p0 = zr[g * 2], p1 = zr[g * 2 + 1];                             \
        float4 p2 = zr[8 + g * 2], p3 = zr[9 + g * 2];                         \
        float t0[8] = {p0.x, p0.y, p0.z, p0.w, p1.x, p1.y, p1.z, p1.w};        \
        float t1[8] = {p2.x, p2.y, p2.z, p2.w, p3.x, p3.y, p3.z, p3.w};        \
        float s = 0.f;                                                         \
        _Pragma("unroll")                                                      \
        for (int e = 0; e < 8; ++e) {                                          \
            s += fabsf(t0[e]) + fabsf(t1[e]);                                  \
            float x0 = 2.0f * t0[e]; unsigned short h0 = f2bf_rn(x0);          \
            AH0[e] = (short)h0; AL0[e] = (short)f2bf_rn(x0 - bf2f(h0));        \
            float x1 = 2.0f * t1[e]; unsigned short h1 = f2bf_rn(x1);          \
            AH1[e] = (short)h1; AL1[e] = (short)f2bf_rn(x1 - bf2f(h1));        \
        }                                                                      \
        s += __shfl_xor(s, 16);                                                \
        s += __shfl_xor(s, 32);                                                \
        if (g == 0 && half == 0) rsv[rw * 32 + (P) * 16 + m] = s;              \
    }
    ALOAD(0, a0h0, a0l0, a0h1, a0l1)
    ALOAD(1, a1h0, a1l0, a1h1, a1l1)
#undef ALOAD

    // ---- scan: 32 col-tiles (this half), 2-buffer register prefetch ----
    float bb00 = INFINITY, bb01 = INFINITY, bb02 = INFINITY, bb03 = INFINITY;
    float bb10 = INFINITY, bb11 = INFINITY, bb12 = INFINITY, bb13 = INFINITY;
    float ss00 = INFINITY, ss01 = INFINITY, ss02 = INFINITY, ss03 = INFINITY;
    float ss10 = INFINITY, ss11 = INFINITY, ss12 = INFINITY, ss13 = INFINITY;
    int   ii00 = 0, ii01 = 0, ii02 = 0, ii03 = 0;
    int   ii10 = 0, ii11 = 0, ii12 = 0, ii13 = 0;
#define UPD(S, B0, B1, I0) { float _s = (S);                                   \
        if (_s < B0) { B1 = B0; B0 = _s; I0 = j; } else B1 = fminf(B1, _s); }

    const bf16x8* pBh = reinterpret_cast<const bf16x8*>(ebh);
    const bf16x8* pBl = reinterpret_cast<const bf16x8*>(ebl);
    const int ct0 = half * 32;

    bf16x8 Ah0 = pBh[ct0 * 128 + lane],        Ah1 = pBh[ct0 * 128 + lane + 64];
    bf16x8 Al0 = pBl[ct0 * 128 + lane],        Al1 = pBl[ct0 * 128 + lane + 64];
    bf16x8 Bh0 = pBh[(ct0 + 1) * 128 + lane],  Bh1 = pBh[(ct0 + 1) * 128 + lane + 64];
    bf16x8 Bl0 = pBl[(ct0 + 1) * 128 + lane],  Bl1 = pBl[(ct0 + 1) * 128 + lane + 64];

    // 6-deep C-in accumulation chain (fixed order, deterministic)
#define COLTILE(CT, VH0, VH1, VL0, VL1) {                                      \
        const int j = (CT) * 16 + m;                                           \
        const float hj = sh_h[j];                                              \
        const f32x4 z4 = {0.f, 0.f, 0.f, 0.f};                                 \
        f32x4 s0 = MFMA(a0h0, VH0, z4);                                        \
        f32x4 s1 = MFMA(a1h0, VH0, z4);                                        \
        s0 = MFMA(a0h1, VH1, s0);                                              \
        s1 = MFMA(a1h1, VH1, s1);                                              \
        s0 = MFMA(a0h0, VL0, s0);                                              \
        s1 = MFMA(a1h0, VL0, s1);                                              \
        s0 = MFMA(a0h1, VL1, s0);                                              \
        s1 = MFMA(a1h1, VL1, s1);                                              \
        s0 = MFMA(a0l0, VH0, s0);                                              \
        s1 = MFMA(a1l0, VH0, s1);                                              \
        s0 = MFMA(a0l1, VH1, s0);                                              \
        s1 = MFMA(a1l1, VH1, s1);                                              \
        UPD(hj - s0[0], bb00, ss00, ii00)                                      \
        UPD(hj - s0[1], bb01, ss01, ii01)                                      \
        UPD(hj - s0[2], bb02, ss02, ii02)                                      \
        UPD(hj - s0[3], bb03, ss03, ii03)                                      \
        UPD(hj - s1[0], bb10, ss10, ii10)                                      \
        UPD(hj - s1[1], bb11, ss11, ii11)                                      \
        UPD(hj - s1[2], bb12, ss12, ii12)                                      \
        UPD(hj - s1[3], bb13, ss13, ii13)                                      \
    }

#pragma unroll 1
    for (int ct = ct0; ct < ct0 + 32; ct += 2) {
        COLTILE(ct, Ah0, Ah1, Al0, Al1);
        if (ct + 2 < ct0 + 32) {
            const int fb = (ct + 2) * 128 + lane;
            Ah0 = pBh[fb]; Ah1 = pBh[fb + 64];
            Al0 = pBl[fb]; Al1 = pBl[fb + 64];
        }
        COLTILE(ct + 1, Bh0, Bh1, Bl0, Bl1);
        if (ct + 3 < ct0 + 32) {
            const int fb = (ct + 3) * 128 + lane;
            Bh0 = pBh[fb]; Bh1 = pBh[fb + 64];
            Bl0 = pBl[fb]; Bl1 = pBl[fb + 64];
        }
    }
#undef COLTILE
#undef UPD

    // ---- reduce best/2nd across the 16 col-lanes of each group ----
#pragma unroll
    for (int mask = 1; mask < 16; mask <<= 1) {
#define MRG(B0, I0, B1) { float ob0 = __shfl_xor(B0, mask); int oi = __shfl_xor(I0, mask); \
        float ob1 = __shfl_xor(B1, mask); \
        if (ob0 < B0) { B1 = fminf(fminf(B0, B1), ob1); B0 = ob0; I0 = oi; } \
        else { B1 = fminf(B1, fminf(ob0, ob1)); } }
        MRG(bb00, ii00, ss00) MRG(bb01, ii01, ss01)
        MRG(bb02, ii02, ss02) MRG(bb03, ii03, ss03)
        MRG(bb10, ii10, ss10) MRG(bb11, ii11, ss11)
        MRG(bb12, ii12, ss12) MRG(bb13, ii13, ss13)
#undef MRG
    }

    // ---- publish per-row partials to LDS (m==0 lane of each group) ----
    if (m == 0) {
        const int r0 = rw * 32 + g * 4;
        sb0[half][r0 + 0] = bb00; sb1[half][r0 + 0] = ss00; sbi[half][r0 + 0] = ii00;
        sb0[half][r0 + 1] = bb01; sb1[half][r0 + 1] = ss01; sbi[half][r0 + 1] = ii01;
        sb0[half][r0 + 2] = bb02; sb1[half][r0 + 2] = ss02; sbi[half][r0 + 2] = ii02;
        sb0[half][r0 + 3] = bb03; sb1[half][r0 + 3] = ss03; sbi[half][r0 + 3] = ii03;
        const int r1 = r0 + 16;
        sb0[half][r1 + 0] = bb10; sb1[half][r1 + 0] = ss10; sbi[half][r1 + 0] = ii10;
        sb0[half][r1 + 1] = bb11; sb1[half][r1 + 1] = ss11; sbi[half][r1 + 1] = ii11;
        sb0[half][r1 + 2] = bb12; sb1[half][r1 + 2] = ss12; sbi[half][r1 + 2] = ii12;
        sb0[half][r1 + 3] = bb13; sb1[half][r1 + 3] = ss13; sbi[half][r1 + 3] = ii13;
    }
    __syncthreads();

    // ---- merge halves + epilogue: 4 threads per row (512 thr / 128 rows) ----
    {
        const int rloc = threadIdx.x >> 2, q = threadIdx.x & 3;
        const int rowO = blockIdx.x * 128 + rloc;
        float b0 = sb0[0][rloc], b1 = sb1[0][rloc];
        int   vi = sbi[0][rloc];
        {
            float c0 = sb0[1][rloc], c1 = sb1[1][rloc];
            int   ci = sbi[1][rloc];
            if (c0 < b0) { b1 = fminf(b0, c1); b0 = c0; vi = ci; }
            else         { b1 = fminf(b1, c0); }   // tie -> half 0 (lower j)
        }
        const float Delta = 6e-8f * rsv[rloc] + 2.2e-5f;
        float local = 0.f;
        if (b1 - b0 <= Delta) {
            if (q == 0) { unsigned p = atomicAdd(flagN, 1u); flagL[p] = (unsigned)rowO; }
        } else {
            if (q == 0) { out_idx[rowO] = (float)vi; atomicAdd(&hist[vi], 1u); }
            const float4* cv = reinterpret_cast<const float4*>(cb + (size_t)vi * 64) + q * 4;
            const float4* zv = reinterpret_cast<const float4*>(z + (size_t)rowO * 64) + q * 4;
            float* orow = out_zq + (size_t)rowO * 64 + q * 16;
#pragma unroll
            for (int u = 0; u < 4; ++u) {
                float4 cc = cv[u], zo = zv[u];
                orow[4 * u + 0] = cc.x; orow[4 * u + 1] = cc.y;
                orow[4 * u + 2] = cc.z; orow[4 * u + 3] = cc.w;
                float dx = cc.x - zo.x, dy = cc.y - zo.y;
                float dz = cc.z - zo.z, dw = cc.w - zo.w;
                local = fmaf(dx, dx, local); local = fmaf(dy, dy, local);
                local = fmaf(dz, dz, local); local = fmaf(dw, dw, local);
            }
        }
#pragma unroll
        for (int off = 32; off; off >>= 1) local += __shfl_down(local, off);
        if (lane == 0) wp[w] = local;
    }
    __syncthreads();
    if (threadIdx.x == 0) {
        float t = ((wp[0] + wp[1]) + (wp[2] + wp[3]))
                + ((wp[4] + wp[5]) + (wp[6] + wp[7]));
        atomicAdd(sse, (double)t);
    }
}

// Exact re-scan for flagged rows: one wave per row, 16 codes per lane.
__global__ __launch_bounds__(64, 4) void k_cleanup(
    const float* __restrict__ z, const float* __restrict__ cb,
    const float* __restrict__ h,
    const unsigned* __restrict__ flagN, const unsigned* __restrict__ flagL,
    float* __restrict__ out_zq, float* __restrict__ out_idx,
    unsigned* __restrict__ hist, double* __restrict__ sse) {
    const unsigned n = *flagN;
    const int lane = threadIdx.x;

    for (unsigned f = blockIdx.x; f < n; f += gridDim.x) {
        const int row = (int)flagL[f];

        float tz[E_DIM];
        const float4* zp = reinterpret_cast<const float4*>(z + (size_t)row * 64);
#pragma unroll
        for (int k4 = 0; k4 < 16; ++k4) {
            float4 v = zp[k4];
            tz[4 * k4 + 0] = v.x; tz[4 * k4 + 1] = v.y;
            tz[4 * k4 + 2] = v.z; tz[4 * k4 + 3] = v.w;
        }
        const float nz = pw64_sq(tz);
#pragma unroll
        for (int k = 0; k < 64; ++k) tz[k] = 2.0f * tz[k];

        float bs = INFINITY;
        int bj = 0;
#pragma unroll 2
        for (int t = 0; t < 16; ++t) {
            const int j = lane + 64 * t;
            const float4* cv = reinterpret_cast<const float4*>(cb + (size_t)j * 64);
            float mm = 0.f;
#pragma unroll
            for (int k4 = 0; k4 < 16; ++k4) {
                float4 e = cv[k4];
                mm = fmaf(tz[4 * k4 + 0], e.x, mm);
                mm = fmaf(tz[4 * k4 + 1], e.y, mm);
                mm = fmaf(tz[4 * k4 + 2], e.z, mm);
                mm = fmaf(tz[4 * k4 + 3], e.w, mm);
            }
            float sc = (nz + h[j]) - mm;
            if (sc < bs) { bs = sc; bj = j; }
        }
#pragma unroll
        for (int off = 32; off; off >>= 1) {
            float s2 = __shfl_down(bs, off);
            int   j2 = __shfl_down(bj, off);
            if (s2 < bs || (s2 == bs && j2 < bj)) { bs = s2; bj = j2; }
        }
        bj = __shfl(bj, 0);

        float c = cb[(size_t)bj * 64 + lane];
        out_zq[(size_t)row * 64 + lane] = c;
        float d = c - 0.5f * tz[lane];
        float l2 = d * d;
#pragma unroll
        for (int off = 32; off; off >>= 1) l2 += __shfl_down(l2, off);
        if (lane == 0) {
            out_idx[row] = (float)bj;
            atomicAdd(&hist[bj], 1u);
            atomicAdd(sse, (double)l2);
        }
    }
}

// ---- round-5 fallback scan (only if ws_size is too small) ----
__global__ __launch_bounds__(256) void k_h_fb(const float* __restrict__ cb,
                                              float* __restrict__ h) {
    int j = blockIdx.x * 256 + threadIdx.x;
    if (j < N_E) {
        float e[E_DIM];
        const float4* ep = reinterpret_cast<const float4*>(cb + (size_t)j * E_DIM);
#pragma unroll
        for (int k4 = 0; k4 < E_DIM / 4; ++k4) {
            float4 v = ep[k4];
            e[4 * k4 + 0] = v.x; e[4 * k4 + 1] = v.y;
            e[4 * k4 + 2] = v.z; e[4 * k4 + 3] = v.w;
        }
        h[j] = pw64_sq(e);
    }
}

__global__ __launch_bounds__(512, 2) void k_scan_fb(
    const float* __restrict__ z, const float* __restrict__ cb,
    const float* __restrict__ h,
    float* __restrict__ out_zq, float* __restrict__ out_idx,
    unsigned* __restrict__ hist, double* __restrict__ sse) {
    const int lane = threadIdx.x & 63;
    const int w = __builtin_amdgcn_readfirstlane(threadIdx.x >> 6);
    const int row = blockIdx.x * 64 + lane;
    float tz[E_DIM];
    const float4* zp = reinterpret_cast<const float4*>(z + (size_t)row * E_DIM);
#pragma unroll
    for (int k4 = 0; k4 < E_DIM / 4; ++k4) {
        float4 v = zp[k4];
        tz[4 * k4 + 0] = v.x; tz[4 * k4 + 1] = v.y;
        tz[4 * k4 + 2] = v.z; tz[4 * k4 + 3] = v.w;
    }
    const float nz = pw64_sq(tz);
#pragma unroll
    for (int k = 0; k < E_DIM; ++k) tz[k] = 2.0f * tz[k];
    float b0 = INFINITY; int bi = 0;
    const int j0 = w * 128;
#pragma unroll 1
    for (int j = j0; j < j0 + 128; j += 4) {
        const float* c0 = cb + (size_t)j * E_DIM;
        float m0 = 0.f, m1 = 0.f, m2 = 0.f, m3 = 0.f;
#pragma unroll
        for (int k = 0; k < E_DIM; ++k) {
            float wk = tz[k];
            m0 = fmaf(wk, c0[0 * E_DIM + k], m0);
            m1 = fmaf(wk, c0[1 * E_DIM + k], m1);
            m2 = fmaf(wk, c0[2 * E_DIM + k], m2);
            m3 = fmaf(wk, c0[3 * E_DIM + k], m3);
        }
        float s0 = (nz + h[j + 0]) - m0;
        float s1 = (nz + h[j + 1]) - m1;
        float s2 = (nz + h[j + 2]) - m2;
        float s3 = (nz + h[j + 3]) - m3;
        if (s0 < b0) { b0 = s0; bi = j + 0; }
        if (s1 < b0) { b0 = s1; bi = j + 1; }
        if (s2 < b0) { b0 = s2; bi = j + 2; }
        if (s3 < b0) { b0 = s3; bi = j + 3; }
    }
    __shared__ float lb[8][64];
    __shared__ int   li[8][64];
    lb[w][lane] = b0; li[w][lane] = bi;
    __syncthreads();
    if (threadIdx.x < 64) {
        float b = lb[0][lane]; int i = li[0][lane];
#pragma unroll
        for (int c = 1; c < 8; ++c) {
            float bc = lb[c][lane]; int ic = li[c][lane];
            if (bc < b) { b = bc; i = ic; }
        }
        out_idx[row] = (float)i;
        float local = 0.f;
        const float4* cv = reinterpret_cast<const float4*>(cb + (size_t)i * E_DIM);
        float* orow = out_zq + (size_t)row * E_DIM;
#pragma unroll
        for (int k4 = 0; k4 < E_DIM / 4; ++k4) {
            float4 c = cv[k4];
            float zx = 0.5f * tz[4 * k4 + 0], zy = 0.5f * tz[4 * k4 + 1];
            float zz = 0.5f * tz[4 * k4 + 2], zw = 0.5f * tz[4 * k4 + 3];
            orow[4 * k4 + 0] = c.x; orow[4 * k4 + 1] = c.y;
            orow[4 * k4 + 2] = c.z; orow[4 * k4 + 3] = c.w;
            float dx = c.x - zx, dy = c.y - zy, dz = c.z - zz, dw = c.w - zw;
            local = fmaf(dx, dx, local); local = fmaf(dy, dy, local);
            local = fmaf(dz, dz, local); local = fmaf(dw, dw, local);
        }
        atomicAdd(&hist[i], 1u);
#pragma unroll
        for (int off = 32; off; off >>= 1) local += __shfl_down(local, off);
        if (lane == 0) atomicAdd(sse, (double)local);
    }
}

__global__ __launch_bounds__(256) void k_final(
    const unsigned* __restrict__ hist, const double* __restrict__ sse,
    float* __restrict__ out, int nrows) {
    __shared__ double sh[256];
    double acc = 0.0;
    for (int j = threadIdx.x; j < N_E; j += 256) {
        double p = (double)hist[j] / (double)nrows;
        acc += p * log(p + 1e-10);
    }
    sh[threadIdx.x] = acc;
    __syncthreads();
    for (int s = 128; s; s >>= 1) {
        if (threadIdx.x < s) sh[threadIdx.x] += sh[threadIdx.x + s];
        __syncthreads();
    }
    if (threadIdx.x == 0) {
        double ntot = (double)nrows * (double)E_DIM;
        out[0] = (float)((1.0 + BETA) * (*sse) / ntot);               // loss
        out[1 + (size_t)nrows * E_DIM] = (float)exp(-sh[0]);          // perplexity
    }
}

extern "C" void kernel_launch(void* const* d_in, const int* in_sizes, int n_in,
                              void* d_out, int out_size, void* d_ws, size_t ws_size,
                              hipStream_t stream) {
    const float* z  = (const float*)d_in[0];
    const float* cb = (const float*)d_in[1];
    const int nrows = in_sizes[0] / E_DIM;   // 65536
    float* out = (float*)d_out;

    char* ws = (char*)d_ws;
    unsigned* hist  = (unsigned*)(ws + 0);
    double*   sse   = (double*)  (ws + 4096);
    unsigned* flagN = (unsigned*)(ws + 4104);
    float*    h     = (float*)   (ws + 4112);
    unsigned short* ebh = (unsigned short*)(ws + 8208);
    unsigned short* ebl = (unsigned short*)(ws + 139280);
    unsigned* flagL = (unsigned*)(ws + 270352);   // 256 KB
    // end of ws use: 270352 + 262144 = 532496 bytes

    float* out_zq  = out + 1;
    float* out_idx = out + 1 + (size_t)nrows * E_DIM + 1;

    if (ws_size >= 532496) {
        k_prep<<<256, 256, 0, stream>>>(cb, ebh, ebl, h, hist, sse, flagN);
        k_mfma<<<nrows / 128, 512, 0, stream>>>(z, cb, h, ebh, ebl,
                                                out_zq, out_idx, hist, sse,
                                                flagN, flagL);
        k_cleanup<<<2048, 64, 0, stream>>>(z, cb, h, flagN, flagL,
                                           out_zq, out_idx, hist, sse);
    } else {
        hipMemsetAsync(d_ws, 0, 4112, stream);
        k_h_fb<<<(N_E + 255) / 256, 256, 0, stream>>>(cb, h);
        k_scan_fb<<<nrows / 64, 512, 0, stream>>>(z, cb, h, out_zq, out_idx, hist, sse);
    }
    k_final<<<1, 256, 0, stream>>>(hist, sse, out, nrows);
}